// Round 1
// baseline (815.575 us; speedup 1.0000x reference)
//
#include <hip/hip_runtime.h>

#define B_ 4
#define T_ 2048
#define C_ 1024
#define H_ 4
#define D_ 256
#define M_ (B_*T_)      /* 8192 */
#define N1_ (4*C_)      /* 4096 */
#define K_ C_           /* 1024 */

typedef unsigned short u16;
typedef unsigned int u32;
typedef __bf16 bf16x8 __attribute__((ext_vector_type(8)));
typedef float f32x4 __attribute__((ext_vector_type(4)));
typedef float vf4 __attribute__((ext_vector_type(4)));

__device__ __forceinline__ u16 f2bf(float f) {
  union { float f; u32 u; } v; v.f = f;
  u32 u = v.u;
  u32 r = (u + 0x7FFFu + ((u >> 16) & 1u)) >> 16;
  return (u16)r;
}
__device__ __forceinline__ float b2f(u16 h) {
  union { u32 u; float f; } v; v.u = ((u32)h) << 16;
  return v.f;
}

// ---------------- cast fp32 -> bf16 ----------------
__global__ void cast_bf16(const float* __restrict__ in, u16* __restrict__ out, int n) {
  int i = blockIdx.x * 256 + threadIdx.x;
  if (i < n) out[i] = f2bf(in[i]);
}

// ---------------- causal depthwise conv (k=4, left pad 3) + SiLU -> bf16 ----------------
__global__ void conv_silu(const float* __restrict__ x, const float* __restrict__ cw,
                          const float* __restrict__ cb, u16* __restrict__ xc) {
  int idx = blockIdx.x * 256 + threadIdx.x;      // (b, t, c) flattened, B*T*C
  int c = idx & (C_ - 1);
  int t = (idx >> 10) & (T_ - 1);
  float acc = cb[c];
  const float* xp = x + (size_t)idx - 3 * C_;    // x[b][t-3][c]
#pragma unroll
  for (int k = 0; k < 4; ++k) {
    if (t - 3 + k >= 0) acc += cw[c * 4 + k] * xp[(size_t)k * C_];
  }
  float s = acc / (1.f + __expf(-acc));          // silu
  xc[idx] = f2bf(s);
}

// ---------------- bf16 MFMA GEMM, C[m][n] = sum_k A[m][k] * Bw[n][k] ----------------
// EPI 0: += bias, tanh on gate-2 slice, store bf16 (gates)
// EPI 1: += bias + residual, store fp32 (final output)
template <int EPI>
__global__ __launch_bounds__(256, 2)
void gemm_bt(const u16* __restrict__ A, const u16* __restrict__ Bw,
             const float* __restrict__ bias, const float* __restrict__ resid,
             u16* __restrict__ obf, float* __restrict__ of32,
             int M, int N, int K)
{
  __shared__ __align__(16) u16 a_s[128 * 72];   // 128 rows x 64 + pad 8
  __shared__ __align__(16) u16 b_s[128 * 72];

  const int tid  = threadIdx.x;
  const int lane = tid & 63;
  const int l15  = lane & 15;
  const int q    = lane >> 4;          // 0..3
  const int wave = tid >> 6;           // 0..3
  const int wm   = (wave >> 1) * 64;
  const int wn   = (wave & 1) * 64;
  const int bm   = blockIdx.y * 128;
  const int bn   = blockIdx.x * 128;

  const int sr = tid >> 3;             // staging row 0..31
  const int sc = (tid & 7) * 8;        // staging col 0..56

  f32x4 acc[4][4];
#pragma unroll
  for (int i = 0; i < 4; ++i)
#pragma unroll
    for (int j = 0; j < 4; ++j) acc[i][j] = (f32x4){0.f, 0.f, 0.f, 0.f};

  for (int k0 = 0; k0 < K; k0 += 64) {
#pragma unroll
    for (int i = 0; i < 4; ++i) {
      int r = sr + i * 32;
      *(vf4*)&a_s[r * 72 + sc] = *(const vf4*)(A + (size_t)(bm + r) * K + k0 + sc);
      *(vf4*)&b_s[r * 72 + sc] = *(const vf4*)(Bw + (size_t)(bn + r) * K + k0 + sc);
    }
    __syncthreads();
#pragma unroll
    for (int kk = 0; kk < 64; kk += 32) {
      bf16x8 af[4], bfr[4];
#pragma unroll
      for (int s = 0; s < 4; ++s)
        af[s] = *(const bf16x8*)&a_s[(wm + s * 16 + l15) * 72 + kk + q * 8];
#pragma unroll
      for (int s = 0; s < 4; ++s)
        bfr[s] = *(const bf16x8*)&b_s[(wn + s * 16 + l15) * 72 + kk + q * 8];
#pragma unroll
      for (int sm = 0; sm < 4; ++sm)
#pragma unroll
        for (int sn = 0; sn < 4; ++sn)
          acc[sm][sn] = __builtin_amdgcn_mfma_f32_16x16x32_bf16(af[sm], bfr[sn], acc[sm][sn], 0, 0, 0);
    }
    __syncthreads();
  }

#pragma unroll
  for (int sm = 0; sm < 4; ++sm) {
#pragma unroll
    for (int r = 0; r < 4; ++r) {
      int row = bm + wm + sm * 16 + q * 4 + r;
#pragma unroll
      for (int sn = 0; sn < 4; ++sn) {
        int col = bn + wn + sn * 16 + l15;
        float v = acc[sm][sn][r] + bias[col];
        if (EPI == 0) {
          if ((col >> 10) == 2) v = tanhf(v);   // z gate
          obf[(size_t)row * N + col] = f2bf(v);
        } else {
          v += resid[(size_t)row * N + col];
          of32[(size_t)row * N + col] = v;
        }
      }
    }
  }
}

// ---------------- sequential sLSTM scan over T; one thread per (b, c) lane ----------------
__global__ void scan_kernel(const u16* __restrict__ gates, u16* __restrict__ h) {
  int tid = blockIdx.x * 256 + threadIdx.x;      // 0..4095
  int b = tid >> 10, c = tid & (C_ - 1);
  const u16* g = gates + (size_t)b * T_ * N1_ + c;
  u16* hp = h + (size_t)b * T_ * C_ + c;
  float cc = 0.f, nn = 1.f, mm = 0.f;
  for (int t = 0; t < T_; ++t) {
    const u16* gt = g + (size_t)t * N1_;
    float i_t = b2f(gt[0]);
    float f_t = b2f(gt[C_]);
    float z_t = b2f(gt[2 * C_]);                 // tanh already applied
    float o_t = b2f(gt[3 * C_]);
    float m_new = fmaxf(f_t + mm, i_t);
    float i_p = __expf(i_t - m_new);
    float f_p = __expf(f_t + mm - m_new);
    cc = f_p * cc + i_p * z_t;
    nn = f_p * nn + i_p;
    mm = m_new;
    float sig_o = 1.f / (1.f + __expf(-o_t));
    hp[(size_t)t * C_] = f2bf(sig_o * (cc / (nn + 1e-6f)));
  }
}

// ---------------- GroupNorm stats (sum, sumsq) per (b, h) over (T, D) ----------------
__global__ void zero_stats(float* stats) {
  if (threadIdx.x < 32) stats[threadIdx.x] = 0.f;
}

__global__ void stats_kernel(const u16* __restrict__ h, float* __restrict__ stats) {
  int grp = blockIdx.x >> 5;          // 0..15 : b*4 + hh
  int slice = blockIdx.x & 31;        // t-slice of 64
  int b = grp >> 2, hh = grp & 3;
  int d = threadIdx.x;                // 0..255
  const u16* base = h + (size_t)b * T_ * C_ + hh * D_ + d;
  float s = 0.f, sq = 0.f;
  int t0 = slice * 64;
  for (int t = t0; t < t0 + 64; ++t) {
    float v = b2f(base[(size_t)t * C_]);
    s += v; sq += v * v;
  }
  __shared__ float rs[256], rq[256];
  rs[d] = s; rq[d] = sq;
  __syncthreads();
  for (int off = 128; off > 0; off >>= 1) {
    if (d < off) { rs[d] += rs[d + off]; rq[d] += rq[d + off]; }
    __syncthreads();
  }
  if (d == 0) {
    atomicAdd(&stats[grp * 2 + 0], rs[0]);
    atomicAdd(&stats[grp * 2 + 1], rq[0]);
  }
}

// ---------------- apply GroupNorm -> bf16 hn ----------------
__global__ void norm_kernel(const u16* __restrict__ h, const float* __restrict__ stats,
                            const float* __restrict__ gn_w, const float* __restrict__ gn_b,
                            u16* __restrict__ hn) {
  int idx = blockIdx.x * 256 + threadIdx.x;     // 0..M*C-1
  int c = idx & (C_ - 1);
  int bt = idx >> 10;
  int b = bt >> 11;                              // /T_
  int hh = c >> 8;                               // /D_
  int grp = b * 4 + hh;
  const float inv_n = 1.f / (float)(T_ * D_);
  float mean = stats[grp * 2 + 0] * inv_n;
  float var  = stats[grp * 2 + 1] * inv_n - mean * mean;
  float rstd = rsqrtf(var + 1e-5f);
  float v = (b2f(h[idx]) - mean) * rstd * gn_w[c] + gn_b[c];
  hn[idx] = f2bf(v);
}

extern "C" void kernel_launch(void* const* d_in, const int* in_sizes, int n_in,
                              void* d_out, int out_size, void* d_ws, size_t ws_size,
                              hipStream_t stream) {
  const float* x      = (const float*)d_in[0];
  const float* conv_w = (const float*)d_in[1];
  const float* conv_b = (const float*)d_in[2];
  const float* wx_w   = (const float*)d_in[3];
  const float* wx_b   = (const float*)d_in[4];
  const float* gn_w   = (const float*)d_in[5];
  const float* gn_b   = (const float*)d_in[6];
  const float* out_w  = (const float*)d_in[7];
  const float* out_b  = (const float*)d_in[8];
  float* out = (float*)d_out;

  char* p = (char*)d_ws;
  u16* xc    = (u16*)p; p += (size_t)M_ * K_ * 2;      // 16.8 MB
  u16* w1    = (u16*)p; p += (size_t)N1_ * K_ * 2;     // 8.4 MB
  u16* w2    = (u16*)p; p += (size_t)C_ * C_ * 2;      // 2.1 MB
  u16* gts   = (u16*)p; p += (size_t)M_ * N1_ * 2;     // 67.1 MB
  u16* hb    = (u16*)p; p += (size_t)M_ * C_ * 2;      // 16.8 MB
  u16* hn    = (u16*)p; p += (size_t)M_ * C_ * 2;      // 16.8 MB
  float* stats = (float*)p; p += 256;

  // weight casts to bf16
  cast_bf16<<<(N1_ * K_) / 256, 256, 0, stream>>>(wx_w, w1, N1_ * K_);
  cast_bf16<<<(C_ * C_) / 256, 256, 0, stream>>>(out_w, w2, C_ * C_);

  // conv + silu
  conv_silu<<<(M_ * C_) / 256, 256, 0, stream>>>(x, conv_w, conv_b, xc);

  // gates GEMM: (8192 x 1024) x (4096 x 1024)^T
  gemm_bt<0><<<dim3(N1_ / 128, M_ / 128), 256, 0, stream>>>(
      xc, w1, wx_b, nullptr, gts, nullptr, M_, N1_, K_);

  // sequential scan
  scan_kernel<<<16, 256, 0, stream>>>(gts, hb);

  // GroupNorm
  zero_stats<<<1, 64, 0, stream>>>(stats);
  stats_kernel<<<512, 256, 0, stream>>>(hb, stats);
  norm_kernel<<<(M_ * C_) / 256, 256, 0, stream>>>(hb, stats, gn_w, gn_b, hn);

  // output GEMM + bias + residual
  gemm_bt<1><<<dim3(C_ / 128, M_ / 128), 256, 0, stream>>>(
      hn, w2, out_b, x, nullptr, out, M_, C_, K_);
}

// Round 2
// 329.365 us; speedup vs baseline: 2.4762x; 2.4762x over previous
//
#include <hip/hip_runtime.h>

#define B_ 4
#define T_ 2048
#define C_ 1024
#define H_ 4
#define D_ 256
#define M_ (B_*T_)      /* 8192 */
#define N1_ (4*C_)      /* 4096 */
#define K_ C_           /* 1024 */
#define LANES_ (B_*C_)  /* 4096 */
#define CHUNK_ 32
#define NCHUNK_ (T_/CHUNK_)  /* 64 */

typedef unsigned short u16;
typedef unsigned int u32;
typedef __bf16 bf16x8 __attribute__((ext_vector_type(8)));
typedef float f32x4 __attribute__((ext_vector_type(4)));
typedef float vf4 __attribute__((ext_vector_type(4)));

__device__ __forceinline__ u16 f2bf(float f) {
  union { float f; u32 u; } v; v.f = f;
  u32 u = v.u;
  u32 r = (u + 0x7FFFu + ((u >> 16) & 1u)) >> 16;
  return (u16)r;
}
__device__ __forceinline__ float b2f(u16 h) {
  union { u32 u; float f; } v; v.u = ((u32)h) << 16;
  return v.f;
}

// ---------------- cast fp32 -> bf16 ----------------
__global__ void cast_bf16(const float* __restrict__ in, u16* __restrict__ out, int n) {
  int i = blockIdx.x * 256 + threadIdx.x;
  if (i < n) out[i] = f2bf(in[i]);
}

// ---------------- causal depthwise conv (k=4, left pad 3) + SiLU -> bf16 ----------------
__global__ void conv_silu(const float* __restrict__ x, const float* __restrict__ cw,
                          const float* __restrict__ cb, u16* __restrict__ xc) {
  int idx = blockIdx.x * 256 + threadIdx.x;      // (b, t, c) flattened, B*T*C
  int c = idx & (C_ - 1);
  int t = (idx >> 10) & (T_ - 1);
  float acc = cb[c];
  const float* xp = x + (size_t)idx - 3 * C_;    // x[b][t-3][c]
#pragma unroll
  for (int k = 0; k < 4; ++k) {
    if (t - 3 + k >= 0) acc += cw[c * 4 + k] * xp[(size_t)k * C_];
  }
  float s = acc / (1.f + __expf(-acc));          // silu
  xc[idx] = f2bf(s);
}

// ---------------- bf16 MFMA GEMM, C[m][n] = sum_k A[m][k] * Bw[n][k] ----------------
template <int EPI>
__global__ __launch_bounds__(256, 2)
void gemm_bt(const u16* __restrict__ A, const u16* __restrict__ Bw,
             const float* __restrict__ bias, const float* __restrict__ resid,
             u16* __restrict__ obf, float* __restrict__ of32,
             int M, int N, int K)
{
  __shared__ __align__(16) u16 a_s[128 * 72];   // 128 rows x 64 + pad 8
  __shared__ __align__(16) u16 b_s[128 * 72];

  const int tid  = threadIdx.x;
  const int lane = tid & 63;
  const int l15  = lane & 15;
  const int q    = lane >> 4;          // 0..3
  const int wave = tid >> 6;           // 0..3
  const int wm   = (wave >> 1) * 64;
  const int wn   = (wave & 1) * 64;
  const int bm   = blockIdx.y * 128;
  const int bn   = blockIdx.x * 128;

  const int sr = tid >> 3;             // staging row 0..31
  const int sc = (tid & 7) * 8;        // staging col 0..56

  f32x4 acc[4][4];
#pragma unroll
  for (int i = 0; i < 4; ++i)
#pragma unroll
    for (int j = 0; j < 4; ++j) acc[i][j] = (f32x4){0.f, 0.f, 0.f, 0.f};

  for (int k0 = 0; k0 < K; k0 += 64) {
#pragma unroll
    for (int i = 0; i < 4; ++i) {
      int r = sr + i * 32;
      *(vf4*)&a_s[r * 72 + sc] = *(const vf4*)(A + (size_t)(bm + r) * K + k0 + sc);
      *(vf4*)&b_s[r * 72 + sc] = *(const vf4*)(Bw + (size_t)(bn + r) * K + k0 + sc);
    }
    __syncthreads();
#pragma unroll
    for (int kk = 0; kk < 64; kk += 32) {
      bf16x8 af[4], bfr[4];
#pragma unroll
      for (int s = 0; s < 4; ++s)
        af[s] = *(const bf16x8*)&a_s[(wm + s * 16 + l15) * 72 + kk + q * 8];
#pragma unroll
      for (int s = 0; s < 4; ++s)
        bfr[s] = *(const bf16x8*)&b_s[(wn + s * 16 + l15) * 72 + kk + q * 8];
#pragma unroll
      for (int sm = 0; sm < 4; ++sm)
#pragma unroll
        for (int sn = 0; sn < 4; ++sn)
          acc[sm][sn] = __builtin_amdgcn_mfma_f32_16x16x32_bf16(af[sm], bfr[sn], acc[sm][sn], 0, 0, 0);
    }
    __syncthreads();
  }

#pragma unroll
  for (int sm = 0; sm < 4; ++sm) {
#pragma unroll
    for (int r = 0; r < 4; ++r) {
      int row = bm + wm + sm * 16 + q * 4 + r;
#pragma unroll
      for (int sn = 0; sn < 4; ++sn) {
        int col = bn + wn + sn * 16 + l15;
        float v = acc[sm][sn][r] + bias[col];
        if (EPI == 0) {
          if ((col >> 10) == 2) v = tanhf(v);   // z gate
          obf[(size_t)row * N + col] = f2bf(v);
        } else {
          v += resid[(size_t)row * N + col];
          of32[(size_t)row * N + col] = v;
        }
      }
    }
  }
}

// ---------------- chunked parallel sLSTM scan ----------------
// Pass A: per (lane, chunk) compute stabilized chunk summary (F, M, bc, bn):
//   transform: C_out = e^F * C_in + e^M * bc ;  N_out = e^F * N_in + e^M * bn
__global__ void scan_passA(const u16* __restrict__ gates,
                           float* __restrict__ sF, float* __restrict__ sM,
                           float* __restrict__ sBc, float* __restrict__ sBn) {
  int tid = blockIdx.x * 256 + threadIdx.x;     // 0 .. LANES_*NCHUNK_-1
  int l = tid & (LANES_ - 1);                   // lane = b*C + c
  int s = tid >> 12;                            // chunk index
  int b = l >> 10, c = l & (C_ - 1);
  const u16* g = gates + (size_t)b * T_ * N1_ + (size_t)(s * CHUNK_) * N1_ + c;
  float F = 0.f, M = -1e30f, bc = 0.f, bn = 0.f;
#pragma unroll 4
  for (int t = 0; t < CHUNK_; ++t) {
    const u16* gt = g + (size_t)t * N1_;
    float i_t = b2f(gt[0]);
    float f_t = b2f(gt[C_]);
    float z_t = b2f(gt[2 * C_]);
    float Mf = M + f_t;
    float Mn = fmaxf(Mf, i_t);
    float ea = __expf(Mf - Mn);
    float eb = __expf(i_t - Mn);
    bc = ea * bc + eb * z_t;
    bn = ea * bn + eb;
    F += f_t;
    M = Mn;
  }
  sF[tid] = F; sM[tid] = M; sBc[tid] = bc; sBn[tid] = bn;
}

// Prefix: per lane, fold the 64 chunk summaries; store incoming state per chunk.
__global__ void scan_prefix(const float* __restrict__ sF, const float* __restrict__ sM,
                            const float* __restrict__ sBc, const float* __restrict__ sBn,
                            float* __restrict__ iC, float* __restrict__ iN,
                            float* __restrict__ iM) {
  int l = blockIdx.x * 256 + threadIdx.x;       // 0..4095
  float ct = 0.f, nt = 1.f, mt = 0.f;           // reference init (c=0, n=1, m=0)
  for (int s = 0; s < NCHUNK_; ++s) {
    int idx = s * LANES_ + l;
    iC[idx] = ct; iN[idx] = nt; iM[idx] = mt;
    float F = sF[idx], M = sM[idx], bc = sBc[idx], bn = sBn[idx];
    float mf = mt + F;
    float mn = fmaxf(mf, M);
    float a = __expf(mf - mn);
    float bcoef = __expf(M - mn);
    ct = a * ct + bcoef * bc;
    nt = a * nt + bcoef * bn;
    mt = mn;
  }
}

// Pass B: replay exact reference recurrence inside each chunk from incoming state.
__global__ void scan_passB(const u16* __restrict__ gates,
                           const float* __restrict__ iC, const float* __restrict__ iN,
                           const float* __restrict__ iM, u16* __restrict__ h) {
  int tid = blockIdx.x * 256 + threadIdx.x;
  int l = tid & (LANES_ - 1);
  int s = tid >> 12;
  int b = l >> 10, c = l & (C_ - 1);
  const u16* g = gates + (size_t)b * T_ * N1_ + (size_t)(s * CHUNK_) * N1_ + c;
  u16* hp = h + (size_t)b * T_ * C_ + (size_t)(s * CHUNK_) * C_ + c;
  float cc = iC[tid], nn = iN[tid], mm = iM[tid];
#pragma unroll 4
  for (int t = 0; t < CHUNK_; ++t) {
    const u16* gt = g + (size_t)t * N1_;
    float i_t = b2f(gt[0]);
    float f_t = b2f(gt[C_]);
    float z_t = b2f(gt[2 * C_]);                 // tanh already applied
    float o_t = b2f(gt[3 * C_]);
    float m_new = fmaxf(f_t + mm, i_t);
    float i_p = __expf(i_t - m_new);
    float f_p = __expf(f_t + mm - m_new);
    cc = f_p * cc + i_p * z_t;
    nn = f_p * nn + i_p;
    mm = m_new;
    float sig_o = 1.f / (1.f + __expf(-o_t));
    hp[(size_t)t * C_] = f2bf(sig_o * (cc / (nn + 1e-6f)));
  }
}

// ---------------- GroupNorm stats (sum, sumsq) per (b, h) over (T, D) ----------------
__global__ void zero_stats(float* stats) {
  if (threadIdx.x < 32) stats[threadIdx.x] = 0.f;
}

__global__ void stats_kernel(const u16* __restrict__ h, float* __restrict__ stats) {
  int grp = blockIdx.x >> 5;          // 0..15 : b*4 + hh
  int slice = blockIdx.x & 31;        // t-slice of 64
  int b = grp >> 2, hh = grp & 3;
  int d = threadIdx.x;                // 0..255
  const u16* base = h + (size_t)b * T_ * C_ + hh * D_ + d;
  float s = 0.f, sq = 0.f;
  int t0 = slice * 64;
  for (int t = t0; t < t0 + 64; ++t) {
    float v = b2f(base[(size_t)t * C_]);
    s += v; sq += v * v;
  }
  __shared__ float rs[256], rq[256];
  rs[d] = s; rq[d] = sq;
  __syncthreads();
  for (int off = 128; off > 0; off >>= 1) {
    if (d < off) { rs[d] += rs[d + off]; rq[d] += rq[d + off]; }
    __syncthreads();
  }
  if (d == 0) {
    atomicAdd(&stats[grp * 2 + 0], rs[0]);
    atomicAdd(&stats[grp * 2 + 1], rq[0]);
  }
}

// ---------------- apply GroupNorm -> bf16 hn ----------------
__global__ void norm_kernel(const u16* __restrict__ h, const float* __restrict__ stats,
                            const float* __restrict__ gn_w, const float* __restrict__ gn_b,
                            u16* __restrict__ hn) {
  int idx = blockIdx.x * 256 + threadIdx.x;     // 0..M*C-1
  int c = idx & (C_ - 1);
  int bt = idx >> 10;
  int b = bt >> 11;                              // /T_
  int hh = c >> 8;                               // /D_
  int grp = b * 4 + hh;
  const float inv_n = 1.f / (float)(T_ * D_);
  float mean = stats[grp * 2 + 0] * inv_n;
  float var  = stats[grp * 2 + 1] * inv_n - mean * mean;
  float rstd = rsqrtf(var + 1e-5f);
  float v = (b2f(h[idx]) - mean) * rstd * gn_w[c] + gn_b[c];
  hn[idx] = f2bf(v);
}

extern "C" void kernel_launch(void* const* d_in, const int* in_sizes, int n_in,
                              void* d_out, int out_size, void* d_ws, size_t ws_size,
                              hipStream_t stream) {
  const float* x      = (const float*)d_in[0];
  const float* conv_w = (const float*)d_in[1];
  const float* conv_b = (const float*)d_in[2];
  const float* wx_w   = (const float*)d_in[3];
  const float* wx_b   = (const float*)d_in[4];
  const float* gn_w   = (const float*)d_in[5];
  const float* gn_b   = (const float*)d_in[6];
  const float* out_w  = (const float*)d_in[7];
  const float* out_b  = (const float*)d_in[8];
  float* out = (float*)d_out;

  char* p = (char*)d_ws;
  u16* xc    = (u16*)p; p += (size_t)M_ * K_ * 2;      // 16.8 MB
  u16* w1    = (u16*)p; p += (size_t)N1_ * K_ * 2;     // 8.4 MB
  u16* w2    = (u16*)p; p += (size_t)C_ * C_ * 2;      // 2.1 MB
  u16* gts   = (u16*)p; p += (size_t)M_ * N1_ * 2;     // 67.1 MB
  u16* hb    = (u16*)p; p += (size_t)M_ * C_ * 2;      // 16.8 MB
  u16* hn    = (u16*)p; p += (size_t)M_ * C_ * 2;      // 16.8 MB
  float* stats = (float*)p; p += 256;
  const int nsum = LANES_ * NCHUNK_;                   // 256K
  float* sF  = (float*)p; p += (size_t)nsum * 4;       // 1 MB each
  float* sM  = (float*)p; p += (size_t)nsum * 4;
  float* sBc = (float*)p; p += (size_t)nsum * 4;
  float* sBn = (float*)p; p += (size_t)nsum * 4;
  float* iC  = (float*)p; p += (size_t)nsum * 4;
  float* iN  = (float*)p; p += (size_t)nsum * 4;
  float* iM  = (float*)p; p += (size_t)nsum * 4;

  // weight casts to bf16
  cast_bf16<<<(N1_ * K_) / 256, 256, 0, stream>>>(wx_w, w1, N1_ * K_);
  cast_bf16<<<(C_ * C_) / 256, 256, 0, stream>>>(out_w, w2, C_ * C_);

  // conv + silu
  conv_silu<<<(M_ * C_) / 256, 256, 0, stream>>>(x, conv_w, conv_b, xc);

  // gates GEMM: (8192 x 1024) x (4096 x 1024)^T
  gemm_bt<0><<<dim3(N1_ / 128, M_ / 128), 256, 0, stream>>>(
      xc, w1, wx_b, nullptr, gts, nullptr, M_, N1_, K_);

  // chunked parallel scan
  scan_passA<<<nsum / 256, 256, 0, stream>>>(gts, sF, sM, sBc, sBn);
  scan_prefix<<<LANES_ / 256, 256, 0, stream>>>(sF, sM, sBc, sBn, iC, iN, iM);
  scan_passB<<<nsum / 256, 256, 0, stream>>>(gts, iC, iN, iM, hb);

  // GroupNorm
  zero_stats<<<1, 64, 0, stream>>>(stats);
  stats_kernel<<<512, 256, 0, stream>>>(hb, stats);
  norm_kernel<<<(M_ * C_) / 256, 256, 0, stream>>>(hb, stats, gn_w, gn_b, hn);

  // output GEMM + bias + residual
  gemm_bt<1><<<dim3(C_ / 128, M_ / 128), 256, 0, stream>>>(
      hn, w2, out_b, x, nullptr, out, M_, C_, K_);
}

// Round 3
// 287.495 us; speedup vs baseline: 2.8368x; 1.1456x over previous
//
#include <hip/hip_runtime.h>

#define B_ 4
#define T_ 2048
#define C_ 1024
#define H_ 4
#define D_ 256
#define M_ (B_*T_)      /* 8192 */
#define N1_ (4*C_)      /* 4096 */
#define K_ C_           /* 1024 */
#define LANES_ (B_*C_)  /* 4096 */
#define CHUNK_ 32
#define NCHUNK_ (T_/CHUNK_)  /* 64 */

typedef unsigned short u16;
typedef unsigned int u32;
typedef __bf16 bf16x8 __attribute__((ext_vector_type(8)));
typedef float f32x4 __attribute__((ext_vector_type(4)));
typedef float vf4 __attribute__((ext_vector_type(4)));
typedef unsigned short u16x4 __attribute__((ext_vector_type(4)));
typedef unsigned short u16x8 __attribute__((ext_vector_type(8)));

__device__ __forceinline__ u16 f2bf(float f) {
  union { float f; u32 u; } v; v.f = f;
  u32 u = v.u;
  u32 r = (u + 0x7FFFu + ((u >> 16) & 1u)) >> 16;
  return (u16)r;
}
__device__ __forceinline__ float b2f(u16 h) {
  union { u32 u; float f; } v; v.u = ((u32)h) << 16;
  return v.f;
}

// ---------------- cast fp32 -> bf16, 8 elems/thread ----------------
__global__ void cast_bf16(const float* __restrict__ in, u16* __restrict__ out) {
  int i8 = (blockIdx.x * 256 + threadIdx.x) * 8;
  vf4 a = *(const vf4*)(in + i8);
  vf4 b = *(const vf4*)(in + i8 + 4);
  u16x8 o;
  o[0] = f2bf(a[0]); o[1] = f2bf(a[1]); o[2] = f2bf(a[2]); o[3] = f2bf(a[3]);
  o[4] = f2bf(b[0]); o[5] = f2bf(b[1]); o[6] = f2bf(b[2]); o[7] = f2bf(b[3]);
  *(u16x8*)(out + i8) = o;
}

// ---------------- causal depthwise conv (k=4, left pad 3) + SiLU -> bf16 ----------------
// 4 channels/thread; also zeroes the stats buffer (used later by scan_passB).
__global__ void conv_silu(const float* __restrict__ x, const float* __restrict__ cw,
                          const float* __restrict__ cb, u16* __restrict__ xc,
                          float* __restrict__ stats) {
  if (blockIdx.x == 0 && threadIdx.x < 32) stats[threadIdx.x] = 0.f;
  int i4 = (blockIdx.x * 256 + threadIdx.x) * 4;   // (b,t,c4) flattened
  int c = i4 & (C_ - 1);
  int t = (i4 >> 10) & (T_ - 1);
  vf4 acc = *(const vf4*)(cb + c);
  vf4 w0 = *(const vf4*)(cw + (size_t)c * 4);
  vf4 w1 = *(const vf4*)(cw + (size_t)(c + 1) * 4);
  vf4 w2 = *(const vf4*)(cw + (size_t)(c + 2) * 4);
  vf4 w3 = *(const vf4*)(cw + (size_t)(c + 3) * 4);
#pragma unroll
  for (int k = 0; k < 4; ++k) {
    if (t - 3 + k >= 0) {
      vf4 xv = *(const vf4*)(x + (size_t)i4 + (size_t)(k - 3) * C_);
      acc[0] = fmaf(w0[k], xv[0], acc[0]);
      acc[1] = fmaf(w1[k], xv[1], acc[1]);
      acc[2] = fmaf(w2[k], xv[2], acc[2]);
      acc[3] = fmaf(w3[k], xv[3], acc[3]);
    }
  }
  u16x4 o;
#pragma unroll
  for (int j = 0; j < 4; ++j) {
    float s = acc[j] / (1.f + __expf(-acc[j]));
    o[j] = f2bf(s);
  }
  *(u16x4*)(xc + i4) = o;
}

// ---------------- bf16 MFMA GEMM, C[m][n] = sum_k A[m][k] * Bw[n][k] ----------------
// global_load_lds (16B) staging with XOR chunk swizzle: LDS row r (64 u16 = 8
// chunks of 16B) stores logical chunk cl at physical slot cl ^ (r & 7).
template <int EPI>
__global__ __launch_bounds__(256, 2)
void gemm_bt(const u16* __restrict__ A, const u16* __restrict__ Bw,
             const float* __restrict__ bias, const float* __restrict__ resid,
             u16* __restrict__ obf, float* __restrict__ of32,
             int M, int N, int K)
{
  __shared__ __align__(16) u16 a_s[128 * 64];
  __shared__ __align__(16) u16 b_s[128 * 64];

  const int tid  = threadIdx.x;
  const int lane = tid & 63;
  const int l15  = lane & 15;
  const int q    = lane >> 4;          // 0..3
  const int wave = tid >> 6;           // 0..3
  const int wm   = (wave >> 1) * 64;
  const int wn   = (wave & 1) * 64;
  const int bm   = blockIdx.y * 128;
  const int bn   = blockIdx.x * 128;

  const int srow   = wave * 8 + (lane >> 3);   // row within 32-row issue group
  const int schunk = lane & 7;                 // physical 16B chunk this lane fills

  f32x4 acc[4][4];
#pragma unroll
  for (int i = 0; i < 4; ++i)
#pragma unroll
    for (int j = 0; j < 4; ++j) acc[i][j] = (f32x4){0.f, 0.f, 0.f, 0.f};

  for (int k0 = 0; k0 < K; k0 += 64) {
#pragma unroll
    for (int i = 0; i < 4; ++i) {
      int r = i * 32 + srow;                   // absolute LDS row 0..127
      int lc = schunk ^ (r & 7);               // logical chunk to fetch
      const u16* ga = A  + (size_t)(bm + r) * K + k0 + lc * 8;
      const u16* gb = Bw + (size_t)(bn + r) * K + k0 + lc * 8;
      __builtin_amdgcn_global_load_lds(
          (const __attribute__((address_space(1))) u32*)ga,
          (__attribute__((address_space(3))) u32*)&a_s[(i * 32 + wave * 8) * 64],
          16, 0, 0);
      __builtin_amdgcn_global_load_lds(
          (const __attribute__((address_space(1))) u32*)gb,
          (__attribute__((address_space(3))) u32*)&b_s[(i * 32 + wave * 8) * 64],
          16, 0, 0);
    }
    __syncthreads();
#pragma unroll
    for (int kk = 0; kk < 64; kk += 32) {
      const int kc = kk >> 3;                  // 0 or 4
      bf16x8 af[4], bfr[4];
#pragma unroll
      for (int s = 0; s < 4; ++s) {
        int ra = wm + s * 16 + l15;
        int ph = (kc + q) ^ (ra & 7);
        af[s] = *(const bf16x8*)&a_s[ra * 64 + ph * 8];
      }
#pragma unroll
      for (int s = 0; s < 4; ++s) {
        int rb = wn + s * 16 + l15;
        int ph = (kc + q) ^ (rb & 7);
        bfr[s] = *(const bf16x8*)&b_s[rb * 64 + ph * 8];
      }
#pragma unroll
      for (int sm = 0; sm < 4; ++sm)
#pragma unroll
        for (int sn = 0; sn < 4; ++sn)
          acc[sm][sn] = __builtin_amdgcn_mfma_f32_16x16x32_bf16(af[sm], bfr[sn], acc[sm][sn], 0, 0, 0);
    }
    __syncthreads();
  }

#pragma unroll
  for (int sm = 0; sm < 4; ++sm) {
#pragma unroll
    for (int r = 0; r < 4; ++r) {
      int row = bm + wm + sm * 16 + q * 4 + r;
#pragma unroll
      for (int sn = 0; sn < 4; ++sn) {
        int col = bn + wn + sn * 16 + l15;
        float v = acc[sm][sn][r] + bias[col];
        if (EPI == 0) {
          if ((col >> 10) == 2) {               // z gate: tanh (block-uniform branch)
            float e = __expf(2.f * v);
            v = (e - 1.f) / (e + 1.f);
          }
          obf[(size_t)row * N + col] = f2bf(v);
        } else {
          v += resid[(size_t)row * N + col];
          of32[(size_t)row * N + col] = v;
        }
      }
    }
  }
}

// ---------------- chunked parallel sLSTM scan (2 channels/thread) ----------------
__global__ void scan_passA(const u16* __restrict__ gates,
                           float* __restrict__ sF, float* __restrict__ sM,
                           float* __restrict__ sBc, float* __restrict__ sBn) {
  int tid = blockIdx.x * 256 + threadIdx.x;     // 0 .. 2048*64-1
  int lp = tid & 2047;                          // channel-pair index
  int s = tid >> 11;                            // chunk
  int b = lp >> 9;
  int c2 = (lp & 511) * 2;
  const u16* g = gates + (size_t)b * T_ * N1_ + (size_t)(s * CHUNK_) * N1_ + c2;
  float F0 = 0.f, M0 = -1e30f, bc0 = 0.f, bn0 = 0.f;
  float F1 = 0.f, M1 = -1e30f, bc1 = 0.f, bn1 = 0.f;
#pragma unroll 4
  for (int t = 0; t < CHUNK_; ++t) {
    const u16* gt = g + (size_t)t * N1_;
    u32 iw = *(const u32*)(gt);
    u32 fw = *(const u32*)(gt + C_);
    u32 zw = *(const u32*)(gt + 2 * C_);
    {
      float i_t = b2f((u16)iw), f_t = b2f((u16)fw), z_t = b2f((u16)zw);
      float Mf = M0 + f_t;
      float Mn = fmaxf(Mf, i_t);
      float ea = __expf(Mf - Mn), eb = __expf(i_t - Mn);
      bc0 = ea * bc0 + eb * z_t; bn0 = ea * bn0 + eb; F0 += f_t; M0 = Mn;
    }
    {
      float i_t = b2f((u16)(iw >> 16)), f_t = b2f((u16)(fw >> 16)), z_t = b2f((u16)(zw >> 16));
      float Mf = M1 + f_t;
      float Mn = fmaxf(Mf, i_t);
      float ea = __expf(Mf - Mn), eb = __expf(i_t - Mn);
      bc1 = ea * bc1 + eb * z_t; bn1 = ea * bn1 + eb; F1 += f_t; M1 = Mn;
    }
  }
  int idx = s * LANES_ + b * C_ + c2;
  sF[idx] = F0; sM[idx] = M0; sBc[idx] = bc0; sBn[idx] = bn0;
  sF[idx + 1] = F1; sM[idx + 1] = M1; sBc[idx + 1] = bc1; sBn[idx + 1] = bn1;
}

// Prefix: per lane, fold 64 chunk summaries; store incoming state per chunk.
__global__ void scan_prefix(const float* __restrict__ sF, const float* __restrict__ sM,
                            const float* __restrict__ sBc, const float* __restrict__ sBn,
                            float* __restrict__ iC, float* __restrict__ iN,
                            float* __restrict__ iM) {
  int l = blockIdx.x * 256 + threadIdx.x;       // 0..4095
  float ct = 0.f, nt = 1.f, mt = 0.f;           // reference init
  for (int s = 0; s < NCHUNK_; ++s) {
    int idx = s * LANES_ + l;
    iC[idx] = ct; iN[idx] = nt; iM[idx] = mt;
    float F = sF[idx], M = sM[idx], bc = sBc[idx], bn = sBn[idx];
    float mf = mt + F;
    float mn = fmaxf(mf, M);
    float a = __expf(mf - mn);
    float bcoef = __expf(M - mn);
    ct = a * ct + bcoef * bc;
    nt = a * nt + bcoef * bn;
    mt = mn;
  }
}

// Pass B: replay exact reference recurrence; fused GroupNorm stats accumulation.
__global__ void scan_passB(const u16* __restrict__ gates,
                           const float* __restrict__ iC, const float* __restrict__ iN,
                           const float* __restrict__ iM, u16* __restrict__ h,
                           float* __restrict__ stats) {
  int tid = blockIdx.x * 256 + threadIdx.x;
  int lp = tid & 2047;
  int s = tid >> 11;
  int b = lp >> 9;
  int c2 = (lp & 511) * 2;
  const u16* g = gates + (size_t)b * T_ * N1_ + (size_t)(s * CHUNK_) * N1_ + c2;
  u16* hp = h + (size_t)b * T_ * C_ + (size_t)(s * CHUNK_) * C_ + c2;
  int idx = s * LANES_ + b * C_ + c2;
  float cc0 = iC[idx], nn0 = iN[idx], mm0 = iM[idx];
  float cc1 = iC[idx + 1], nn1 = iN[idx + 1], mm1 = iM[idx + 1];
  float ls = 0.f, lq = 0.f;
#pragma unroll 4
  for (int t = 0; t < CHUNK_; ++t) {
    const u16* gt = g + (size_t)t * N1_;
    u32 iw = *(const u32*)(gt);
    u32 fw = *(const u32*)(gt + C_);
    u32 zw = *(const u32*)(gt + 2 * C_);
    u32 ow = *(const u32*)(gt + 3 * C_);
    float h0, h1;
    {
      float i_t = b2f((u16)iw), f_t = b2f((u16)fw), z_t = b2f((u16)zw), o_t = b2f((u16)ow);
      float m_new = fmaxf(f_t + mm0, i_t);
      float i_p = __expf(i_t - m_new);
      float f_p = __expf(f_t + mm0 - m_new);
      cc0 = f_p * cc0 + i_p * z_t;
      nn0 = f_p * nn0 + i_p;
      mm0 = m_new;
      float sig_o = 1.f / (1.f + __expf(-o_t));
      h0 = sig_o * (cc0 / (nn0 + 1e-6f));
    }
    {
      float i_t = b2f((u16)(iw >> 16)), f_t = b2f((u16)(fw >> 16));
      float z_t = b2f((u16)(zw >> 16)), o_t = b2f((u16)(ow >> 16));
      float m_new = fmaxf(f_t + mm1, i_t);
      float i_p = __expf(i_t - m_new);
      float f_p = __expf(f_t + mm1 - m_new);
      cc1 = f_p * cc1 + i_p * z_t;
      nn1 = f_p * nn1 + i_p;
      mm1 = m_new;
      float sig_o = 1.f / (1.f + __expf(-o_t));
      h1 = sig_o * (cc1 / (nn1 + 1e-6f));
    }
    // stats accumulate on the bf16-rounded values actually stored
    u16 hb0 = f2bf(h0), hb1 = f2bf(h1);
    float v0 = b2f(hb0), v1 = b2f(hb1);
    ls += v0 + v1; lq += v0 * v0 + v1 * v1;
    *(u32*)(hp + (size_t)t * C_) = (u32)hb0 | ((u32)hb1 << 16);
  }
  // block reduction: threads 0..127 and 128..255 cover two distinct (b,h) groups
  __shared__ float rs[256], rq[256];
  int thr = threadIdx.x;
  rs[thr] = ls; rq[thr] = lq;
  __syncthreads();
  for (int off = 64; off > 0; off >>= 1) {
    if ((thr & 127) < off) { rs[thr] += rs[thr + off]; rq[thr] += rq[thr + off]; }
    __syncthreads();
  }
  if ((thr & 127) == 0) {
    int grp = b * 4 + (c2 >> 8);
    atomicAdd(&stats[grp * 2 + 0], rs[thr]);
    atomicAdd(&stats[grp * 2 + 1], rq[thr]);
  }
}

// ---------------- apply GroupNorm -> bf16 hn (8 elems/thread) ----------------
__global__ void norm_kernel(const u16* __restrict__ h, const float* __restrict__ stats,
                            const float* __restrict__ gn_w, const float* __restrict__ gn_b,
                            u16* __restrict__ hn) {
  int i8 = (blockIdx.x * 256 + threadIdx.x) * 8;
  int c = i8 & (C_ - 1);
  int b = i8 >> 21;                              // / (T_*C_)
  int grp = b * 4 + (c >> 8);
  const float inv_n = 1.f / (float)(T_ * D_);
  float mean = stats[grp * 2 + 0] * inv_n;
  float var  = stats[grp * 2 + 1] * inv_n - mean * mean;
  float rstd = rsqrtf(var + 1e-5f);
  u16x8 hv = *(const u16x8*)(h + i8);
  vf4 w0 = *(const vf4*)(gn_w + c), w1 = *(const vf4*)(gn_w + c + 4);
  vf4 b0 = *(const vf4*)(gn_b + c), b1 = *(const vf4*)(gn_b + c + 4);
  u16x8 o;
#pragma unroll
  for (int j = 0; j < 4; ++j) {
    o[j]     = f2bf((b2f(hv[j])     - mean) * rstd * w0[j] + b0[j]);
    o[j + 4] = f2bf((b2f(hv[j + 4]) - mean) * rstd * w1[j] + b1[j]);
  }
  *(u16x8*)(hn + i8) = o;
}

extern "C" void kernel_launch(void* const* d_in, const int* in_sizes, int n_in,
                              void* d_out, int out_size, void* d_ws, size_t ws_size,
                              hipStream_t stream) {
  const float* x      = (const float*)d_in[0];
  const float* conv_w = (const float*)d_in[1];
  const float* conv_b = (const float*)d_in[2];
  const float* wx_w   = (const float*)d_in[3];
  const float* wx_b   = (const float*)d_in[4];
  const float* gn_w   = (const float*)d_in[5];
  const float* gn_b   = (const float*)d_in[6];
  const float* out_w  = (const float*)d_in[7];
  const float* out_b  = (const float*)d_in[8];
  float* out = (float*)d_out;

  char* p = (char*)d_ws;
  u16* xc    = (u16*)p; p += (size_t)M_ * K_ * 2;      // 16.8 MB
  u16* w1    = (u16*)p; p += (size_t)N1_ * K_ * 2;     // 8.4 MB
  u16* w2    = (u16*)p; p += (size_t)C_ * C_ * 2;      // 2.1 MB
  u16* gts   = (u16*)p; p += (size_t)M_ * N1_ * 2;     // 67.1 MB
  u16* hb    = (u16*)p; p += (size_t)M_ * C_ * 2;      // 16.8 MB
  u16* hn    = (u16*)p; p += (size_t)M_ * C_ * 2;      // 16.8 MB
  float* stats = (float*)p; p += 256;
  const int nsum = LANES_ * NCHUNK_;                   // 256K
  float* sF  = (float*)p; p += (size_t)nsum * 4;
  float* sM  = (float*)p; p += (size_t)nsum * 4;
  float* sBc = (float*)p; p += (size_t)nsum * 4;
  float* sBn = (float*)p; p += (size_t)nsum * 4;
  float* iC  = (float*)p; p += (size_t)nsum * 4;
  float* iN  = (float*)p; p += (size_t)nsum * 4;
  float* iM  = (float*)p; p += (size_t)nsum * 4;

  // weight casts to bf16
  cast_bf16<<<(N1_ * K_) / 2048, 256, 0, stream>>>(wx_w, w1);
  cast_bf16<<<(C_ * C_) / 2048, 256, 0, stream>>>(out_w, w2);

  // conv + silu (also zeroes stats)
  conv_silu<<<(M_ * C_) / 1024, 256, 0, stream>>>(x, conv_w, conv_b, xc, stats);

  // gates GEMM: (8192 x 1024) x (4096 x 1024)^T
  gemm_bt<0><<<dim3(N1_ / 128, M_ / 128), 256, 0, stream>>>(
      xc, w1, wx_b, nullptr, gts, nullptr, M_, N1_, K_);

  // chunked parallel scan
  scan_passA<<<(2048 * NCHUNK_) / 256, 256, 0, stream>>>(gts, sF, sM, sBc, sBn);
  scan_prefix<<<LANES_ / 256, 256, 0, stream>>>(sF, sM, sBc, sBn, iC, iN, iM);
  scan_passB<<<(2048 * NCHUNK_) / 256, 256, 0, stream>>>(gts, iC, iN, iM, hb, stats);

  // GroupNorm apply
  norm_kernel<<<(M_ * C_) / 2048, 256, 0, stream>>>(hb, stats, gn_w, gn_b, hn);

  // output GEMM + bias + residual
  gemm_bt<1><<<dim3(C_ / 128, M_ / 128), 256, 0, stream>>>(
      hn, w2, out_b, x, nullptr, out, M_, C_, K_);
}

// Round 4
// 282.297 us; speedup vs baseline: 2.8891x; 1.0184x over previous
//
#include <hip/hip_runtime.h>

#define B_ 4
#define T_ 2048
#define C_ 1024
#define H_ 4
#define D_ 256
#define M_ (B_*T_)      /* 8192 */
#define N1_ (4*C_)      /* 4096 */
#define K_ C_           /* 1024 */
#define LANES_ (B_*C_)  /* 4096 */
#define CHUNK_ 32
#define NCHUNK_ (T_/CHUNK_)  /* 64 */

typedef unsigned short u16;
typedef unsigned int u32;
typedef __bf16 bf16x8 __attribute__((ext_vector_type(8)));
typedef float f32x4 __attribute__((ext_vector_type(4)));
typedef float vf4 __attribute__((ext_vector_type(4)));
typedef unsigned short u16x4 __attribute__((ext_vector_type(4)));
typedef unsigned short u16x8 __attribute__((ext_vector_type(8)));

__device__ __forceinline__ u16 f2bf(float f) {
  union { float f; u32 u; } v; v.f = f;
  u32 u = v.u;
  u32 r = (u + 0x7FFFu + ((u >> 16) & 1u)) >> 16;
  return (u16)r;
}
__device__ __forceinline__ float b2f(u16 h) {
  union { u32 u; float f; } v; v.u = ((u32)h) << 16;
  return v.f;
}

// ---------------- merged weight cast: w1 (gate-interleave permuted) + w2 ----------------
// w1p[n][k] = wx_w[(n&3)*1024 + (n>>2)][k]  (n = channel*4 + gate)
__global__ void cast_weights(const float* __restrict__ wx_w, const float* __restrict__ out_w,
                             u16* __restrict__ w1p, u16* __restrict__ w2) {
  int i8 = (blockIdx.x * 256 + threadIdx.x) * 8;
  u16x8 o;
  if (i8 < N1_ * K_) {
    int n = i8 >> 10, k8 = i8 & 1023;
    const float* src = wx_w + (size_t)(((n & 3) << 10) | (n >> 2)) * K_ + k8;
    vf4 a = *(const vf4*)src;
    vf4 b = *(const vf4*)(src + 4);
#pragma unroll
    for (int j = 0; j < 4; ++j) { o[j] = f2bf(a[j]); o[j + 4] = f2bf(b[j]); }
    *(u16x8*)(w1p + i8) = o;
  } else {
    int j8 = i8 - N1_ * K_;
    vf4 a = *(const vf4*)(out_w + j8);
    vf4 b = *(const vf4*)(out_w + j8 + 4);
#pragma unroll
    for (int j = 0; j < 4; ++j) { o[j] = f2bf(a[j]); o[j + 4] = f2bf(b[j]); }
    *(u16x8*)(w2 + j8) = o;
  }
}

// ---------------- causal depthwise conv (k=4, left pad 3) + SiLU -> bf16 ----------------
__global__ void conv_silu(const float* __restrict__ x, const float* __restrict__ cw,
                          const float* __restrict__ cb, u16* __restrict__ xc,
                          float* __restrict__ stats) {
  if (blockIdx.x == 0 && threadIdx.x < 32) stats[threadIdx.x] = 0.f;
  int i4 = (blockIdx.x * 256 + threadIdx.x) * 4;
  int c = i4 & (C_ - 1);
  int t = (i4 >> 10) & (T_ - 1);
  vf4 acc = *(const vf4*)(cb + c);
  vf4 w0 = *(const vf4*)(cw + (size_t)c * 4);
  vf4 w1 = *(const vf4*)(cw + (size_t)(c + 1) * 4);
  vf4 w2 = *(const vf4*)(cw + (size_t)(c + 2) * 4);
  vf4 w3 = *(const vf4*)(cw + (size_t)(c + 3) * 4);
#pragma unroll
  for (int k = 0; k < 4; ++k) {
    if (t - 3 + k >= 0) {
      vf4 xv = *(const vf4*)(x + (size_t)i4 + (size_t)(k - 3) * C_);
      acc[0] = fmaf(w0[k], xv[0], acc[0]);
      acc[1] = fmaf(w1[k], xv[1], acc[1]);
      acc[2] = fmaf(w2[k], xv[2], acc[2]);
      acc[3] = fmaf(w3[k], xv[3], acc[3]);
    }
  }
  u16x4 o;
#pragma unroll
  for (int j = 0; j < 4; ++j) {
    float s = acc[j] / (1.f + __expf(-acc[j]));
    o[j] = f2bf(s);
  }
  *(u16x4*)(xc + i4) = o;
}

// ---------------- bf16 MFMA GEMM, C[m][n] = sum_k A[m][k] * Bw[n][k] ----------------
// EPI 0: gates GEMM with interleaved columns (col = ch*4+gate). Epilogue adds
//   permuted bias, tanh on z lanes, writes bf16 gates to global AND stashes the
//   tile in LDS; then 128 threads compute per-(channel,chunk) scan summaries
//   (F, M, bc, bn) — passA fused, bit-identical to reading the bf16 from HBM.
// EPI 1: += bias + residual, store fp32.
template <int EPI>
__global__ __launch_bounds__(256, 2)
void gemm_bt(const u16* __restrict__ A, const u16* __restrict__ Bw,
             const float* __restrict__ bias, const float* __restrict__ resid,
             u16* __restrict__ obf, float* __restrict__ of32,
             f32x4* __restrict__ sSum, int M, int N, int K)
{
  __shared__ __align__(16) u16 smem[128 * 132];   // 33.8 KB; staging uses first 32 KB
  u16* a_s = smem;
  u16* b_s = smem + 128 * 64;

  const int tid  = threadIdx.x;
  const int lane = tid & 63;
  const int l15  = lane & 15;
  const int q    = lane >> 4;
  const int wave = tid >> 6;
  const int wm   = (wave >> 1) * 64;
  const int wn   = (wave & 1) * 64;
  const int bm   = blockIdx.y * 128;
  const int bn   = blockIdx.x * 128;

  const int srow   = wave * 8 + (lane >> 3);
  const int schunk = lane & 7;

  f32x4 acc[4][4];
#pragma unroll
  for (int i = 0; i < 4; ++i)
#pragma unroll
    for (int j = 0; j < 4; ++j) acc[i][j] = (f32x4){0.f, 0.f, 0.f, 0.f};

  for (int k0 = 0; k0 < K; k0 += 64) {
#pragma unroll
    for (int i = 0; i < 4; ++i) {
      int r = i * 32 + srow;
      int lc = schunk ^ (r & 7);
      const u16* ga = A  + (size_t)(bm + r) * K + k0 + lc * 8;
      const u16* gb = Bw + (size_t)(bn + r) * K + k0 + lc * 8;
      __builtin_amdgcn_global_load_lds(
          (const __attribute__((address_space(1))) u32*)ga,
          (__attribute__((address_space(3))) u32*)&a_s[(i * 32 + wave * 8) * 64],
          16, 0, 0);
      __builtin_amdgcn_global_load_lds(
          (const __attribute__((address_space(1))) u32*)gb,
          (__attribute__((address_space(3))) u32*)&b_s[(i * 32 + wave * 8) * 64],
          16, 0, 0);
    }
    __syncthreads();
#pragma unroll
    for (int kk = 0; kk < 64; kk += 32) {
      const int kc = kk >> 3;
      bf16x8 af[4], bfr[4];
#pragma unroll
      for (int s = 0; s < 4; ++s) {
        int ra = wm + s * 16 + l15;
        int ph = (kc + q) ^ (ra & 7);
        af[s] = *(const bf16x8*)&a_s[ra * 64 + ph * 8];
      }
#pragma unroll
      for (int s = 0; s < 4; ++s) {
        int rb = wn + s * 16 + l15;
        int ph = (kc + q) ^ (rb & 7);
        bfr[s] = *(const bf16x8*)&b_s[rb * 64 + ph * 8];
      }
#pragma unroll
      for (int sm = 0; sm < 4; ++sm)
#pragma unroll
        for (int sn = 0; sn < 4; ++sn)
          acc[sm][sn] = __builtin_amdgcn_mfma_f32_16x16x32_bf16(af[sm], bfr[sn], acc[sm][sn], 0, 0, 0);
    }
    __syncthreads();
  }

  if (EPI == 0) {
#pragma unroll
    for (int smi = 0; smi < 4; ++smi) {
#pragma unroll
      for (int r = 0; r < 4; ++r) {
        int lrow = wm + smi * 16 + q * 4 + r;
#pragma unroll
        for (int sni = 0; sni < 4; ++sni) {
          int lcol = wn + sni * 16 + l15;
          int gcol = bn + lcol;
          float v = acc[smi][sni][r] + bias[((gcol & 3) << 10) | (gcol >> 2)];
          if ((l15 & 3) == 2) {                  // z gate lanes: tanh
            float e = __expf(2.f * v);
            v = (e - 1.f) / (e + 1.f);
          }
          u16 hv = f2bf(v);
          obf[(size_t)(bm + lrow) * N + gcol] = hv;
          smem[lrow * 132 + lcol] = hv;          // stash (stride 132: conflict-free)
        }
      }
    }
    __syncthreads();
    if (tid < 128) {                             // fused passA: 32 ch x 4 chunks
      int ch = tid & 31, ck = tid >> 5;
      const u16* sp = smem + (ck * 32) * 132 + ch * 4;
      float F = 0.f, Mx = -1e30f, aBc = 0.f, aBn = 0.f;
#pragma unroll 8
      for (int t = 0; t < CHUNK_; ++t) {
        u16x4 gv = *(const u16x4*)(sp + t * 132);
        float i_t = b2f(gv[0]), f_t = b2f(gv[1]), z_t = b2f(gv[2]);
        float Mf = Mx + f_t;
        float Mn = fmaxf(Mf, i_t);
        float ea = __expf(Mf - Mn), eb = __expf(i_t - Mn);
        aBc = ea * aBc + eb * z_t;
        aBn = ea * aBn + eb;
        F += f_t; Mx = Mn;
      }
      int b = bm >> 11;
      int s = ((bm & 2047) >> 5) + ck;
      int cg = (bn >> 2) + ch;
      sSum[(size_t)s * LANES_ + b * C_ + cg] = (f32x4){F, Mx, aBc, aBn};
    }
  } else {
#pragma unroll
    for (int smi = 0; smi < 4; ++smi) {
#pragma unroll
      for (int r = 0; r < 4; ++r) {
        int row = bm + wm + smi * 16 + q * 4 + r;
#pragma unroll
        for (int sni = 0; sni < 4; ++sni) {
          int col = bn + wn + sni * 16 + l15;
          float v = acc[smi][sni][r] + bias[col] + resid[(size_t)row * N + col];
          of32[(size_t)row * N + col] = v;
        }
      }
    }
  }
}

// ---------------- prefix: fold 64 chunk summaries per lane; float4-packed ----------------
__global__ void scan_prefix(const f32x4* __restrict__ sSum, f32x4* __restrict__ iSt) {
  int l = blockIdx.x * 256 + threadIdx.x;       // 0..4095
  float ct = 0.f, nt = 1.f, mt = 0.f;           // reference init (c=0, n=1, m=0)
#pragma unroll 4
  for (int s = 0; s < NCHUNK_; ++s) {
    int idx = s * LANES_ + l;
    f32x4 S = sSum[idx];
    iSt[idx] = (f32x4){ct, nt, mt, 0.f};
    float mf = mt + S[0];
    float mn = fmaxf(mf, S[1]);
    float a = __expf(mf - mn);
    float bcoef = __expf(S[1] - mn);
    ct = a * ct + bcoef * S[2];
    nt = a * nt + bcoef * S[3];
    mt = mn;
  }
}

// ---------------- passB: exact reference replay per chunk + fused GN stats ----------------
__global__ void scan_passB(const u16* __restrict__ gates, const f32x4* __restrict__ iSt,
                           u16* __restrict__ h, float* __restrict__ stats) {
  int tid = blockIdx.x * 256 + threadIdx.x;
  int lp = tid & 2047;
  int s = tid >> 11;
  int b = lp >> 9;
  int c2 = (lp & 511) * 2;
  const u16* g = gates + ((size_t)(b * T_ + s * CHUNK_) * C_ + c2) * 4;
  u16* hp = h + (size_t)(b * T_ + s * CHUNK_) * C_ + c2;
  int idx = s * LANES_ + b * C_ + c2;
  f32x4 S0 = iSt[idx], S1 = iSt[idx + 1];
  float cc0 = S0[0], nn0 = S0[1], mm0 = S0[2];
  float cc1 = S1[0], nn1 = S1[1], mm1 = S1[2];
  float ls = 0.f, lq = 0.f;
#pragma unroll 4
  for (int t = 0; t < CHUNK_; ++t) {
    u16x8 gv = *(const u16x8*)(g + (size_t)t * C_ * 4);   // [i0 f0 z0 o0 i1 f1 z1 o1]
    float h0, h1;
    {
      float i_t = b2f(gv[0]), f_t = b2f(gv[1]), z_t = b2f(gv[2]), o_t = b2f(gv[3]);
      float m_new = fmaxf(f_t + mm0, i_t);
      float i_p = __expf(i_t - m_new);
      float f_p = __expf(f_t + mm0 - m_new);
      cc0 = f_p * cc0 + i_p * z_t;
      nn0 = f_p * nn0 + i_p;
      mm0 = m_new;
      float sig_o = 1.f / (1.f + __expf(-o_t));
      h0 = sig_o * (cc0 / (nn0 + 1e-6f));
    }
    {
      float i_t = b2f(gv[4]), f_t = b2f(gv[5]), z_t = b2f(gv[6]), o_t = b2f(gv[7]);
      float m_new = fmaxf(f_t + mm1, i_t);
      float i_p = __expf(i_t - m_new);
      float f_p = __expf(f_t + mm1 - m_new);
      cc1 = f_p * cc1 + i_p * z_t;
      nn1 = f_p * nn1 + i_p;
      mm1 = m_new;
      float sig_o = 1.f / (1.f + __expf(-o_t));
      h1 = sig_o * (cc1 / (nn1 + 1e-6f));
    }
    u16 hb0 = f2bf(h0), hb1 = f2bf(h1);
    float v0 = b2f(hb0), v1 = b2f(hb1);
    ls += v0 + v1; lq += v0 * v0 + v1 * v1;
    *(u32*)(hp + (size_t)t * C_) = (u32)hb0 | ((u32)hb1 << 16);
  }
  __shared__ float rs[256], rq[256];
  int thr = threadIdx.x;
  rs[thr] = ls; rq[thr] = lq;
  __syncthreads();
  for (int off = 64; off > 0; off >>= 1) {
    if ((thr & 127) < off) { rs[thr] += rs[thr + off]; rq[thr] += rq[thr + off]; }
    __syncthreads();
  }
  if ((thr & 127) == 0) {
    int grp = b * 4 + (c2 >> 8);
    atomicAdd(&stats[grp * 2 + 0], rs[thr]);
    atomicAdd(&stats[grp * 2 + 1], rq[thr]);
  }
}

// ---------------- apply GroupNorm -> bf16 hn (8 elems/thread) ----------------
__global__ void norm_kernel(const u16* __restrict__ h, const float* __restrict__ stats,
                            const float* __restrict__ gn_w, const float* __restrict__ gn_b,
                            u16* __restrict__ hn) {
  int i8 = (blockIdx.x * 256 + threadIdx.x) * 8;
  int c = i8 & (C_ - 1);
  int b = i8 >> 21;
  int grp = b * 4 + (c >> 8);
  const float inv_n = 1.f / (float)(T_ * D_);
  float mean = stats[grp * 2 + 0] * inv_n;
  float var  = stats[grp * 2 + 1] * inv_n - mean * mean;
  float rstd = rsqrtf(var + 1e-5f);
  u16x8 hv = *(const u16x8*)(h + i8);
  vf4 w0 = *(const vf4*)(gn_w + c), w1 = *(const vf4*)(gn_w + c + 4);
  vf4 b0 = *(const vf4*)(gn_b + c), b1 = *(const vf4*)(gn_b + c + 4);
  u16x8 o;
#pragma unroll
  for (int j = 0; j < 4; ++j) {
    o[j]     = f2bf((b2f(hv[j])     - mean) * rstd * w0[j] + b0[j]);
    o[j + 4] = f2bf((b2f(hv[j + 4]) - mean) * rstd * w1[j] + b1[j]);
  }
  *(u16x8*)(hn + i8) = o;
}

extern "C" void kernel_launch(void* const* d_in, const int* in_sizes, int n_in,
                              void* d_out, int out_size, void* d_ws, size_t ws_size,
                              hipStream_t stream) {
  const float* x      = (const float*)d_in[0];
  const float* conv_w = (const float*)d_in[1];
  const float* conv_b = (const float*)d_in[2];
  const float* wx_w   = (const float*)d_in[3];
  const float* wx_b   = (const float*)d_in[4];
  const float* gn_w   = (const float*)d_in[5];
  const float* gn_b   = (const float*)d_in[6];
  const float* out_w  = (const float*)d_in[7];
  const float* out_b  = (const float*)d_in[8];
  float* out = (float*)d_out;

  char* p = (char*)d_ws;
  u16* xc    = (u16*)p; p += (size_t)M_ * K_ * 2;      // 16.8 MB
  u16* w1    = (u16*)p; p += (size_t)N1_ * K_ * 2;     // 8.4 MB (permuted)
  u16* w2    = (u16*)p; p += (size_t)C_ * C_ * 2;      // 2.1 MB
  u16* gts   = (u16*)p; p += (size_t)M_ * N1_ * 2;     // 67.1 MB (interleaved c*4+g)
  u16* hb    = (u16*)p; p += (size_t)M_ * C_ * 2;      // 16.8 MB
  u16* hn    = (u16*)p; p += (size_t)M_ * C_ * 2;      // 16.8 MB
  float* stats = (float*)p; p += 256;
  const int nsum = LANES_ * NCHUNK_;                   // 256K
  f32x4* sSum = (f32x4*)p; p += (size_t)nsum * 16;     // 4 MB
  f32x4* iSt  = (f32x4*)p; p += (size_t)nsum * 16;     // 4 MB

  // merged weight casts (w1 gate-interleave permute + w2)
  cast_weights<<<(N1_ * K_ + C_ * C_) / 2048, 256, 0, stream>>>(wx_w, out_w, w1, w2);

  // conv + silu (also zeroes stats)
  conv_silu<<<(M_ * C_) / 1024, 256, 0, stream>>>(x, conv_w, conv_b, xc, stats);

  // gates GEMM + fused passA
  gemm_bt<0><<<dim3(N1_ / 128, M_ / 128), 256, 0, stream>>>(
      xc, w1, wx_b, nullptr, gts, nullptr, sSum, M_, N1_, K_);

  // prefix + replay
  scan_prefix<<<LANES_ / 256, 256, 0, stream>>>(sSum, iSt);
  scan_passB<<<(2048 * NCHUNK_) / 256, 256, 0, stream>>>(gts, iSt, hb, stats);

  // GroupNorm apply
  norm_kernel<<<(M_ * C_) / 2048, 256, 0, stream>>>(hb, stats, gn_w, gn_b, hn);

  // output GEMM + bias + residual
  gemm_bt<1><<<dim3(C_ / 128, M_ / 128), 256, 0, stream>>>(
      hn, w2, out_b, x, nullptr, out, nullptr, M_, C_, K_);
}

// Round 5
// 273.915 us; speedup vs baseline: 2.9775x; 1.0306x over previous
//
#include <hip/hip_runtime.h>

#define B_ 4
#define T_ 2048
#define C_ 1024
#define H_ 4
#define D_ 256
#define M_ (B_*T_)      /* 8192 */
#define N1_ (4*C_)      /* 4096 */
#define K_ C_           /* 1024 */
#define LANES_ (B_*C_)  /* 4096 */
#define CHUNK_ 32
#define NCHUNK_ (T_/CHUNK_)  /* 64 */

typedef unsigned short u16;
typedef unsigned int u32;
typedef __bf16 bf16x8 __attribute__((ext_vector_type(8)));
typedef float f32x4 __attribute__((ext_vector_type(4)));
typedef float vf4 __attribute__((ext_vector_type(4)));
typedef unsigned short u16x4 __attribute__((ext_vector_type(4)));
typedef unsigned short u16x8 __attribute__((ext_vector_type(8)));

__device__ __forceinline__ u16 f2bf(float f) {
  union { float f; u32 u; } v; v.f = f;
  u32 u = v.u;
  u32 r = (u + 0x7FFFu + ((u >> 16) & 1u)) >> 16;
  return (u16)r;
}
__device__ __forceinline__ float b2f(u16 h) {
  union { u32 u; float f; } v; v.u = ((u32)h) << 16;
  return v.f;
}

#define NCAST_ ((N1_*K_ + C_*C_) / 2048)   /* 2560 blocks for weight cast */

// ---------------- merged prologue: weight casts + conv+SiLU ----------------
// blocks [0, NCAST_): cast wx_w (gate-interleave permuted) and out_w to bf16.
// blocks [NCAST_, ...): causal depthwise conv (k=4, left pad 3) + SiLU -> bf16.
__global__ void prep_kernel(const float* __restrict__ wx_w, const float* __restrict__ out_w,
                            u16* __restrict__ w1p, u16* __restrict__ w2,
                            const float* __restrict__ x, const float* __restrict__ cw,
                            const float* __restrict__ cb, u16* __restrict__ xc,
                            float* __restrict__ stats) {
  if (blockIdx.x < NCAST_) {
    int i8 = (blockIdx.x * 256 + threadIdx.x) * 8;
    u16x8 o;
    if (i8 < N1_ * K_) {
      int n = i8 >> 10, k8 = i8 & 1023;
      const float* src = wx_w + (size_t)(((n & 3) << 10) | (n >> 2)) * K_ + k8;
      vf4 a = *(const vf4*)src;
      vf4 b = *(const vf4*)(src + 4);
#pragma unroll
      for (int j = 0; j < 4; ++j) { o[j] = f2bf(a[j]); o[j + 4] = f2bf(b[j]); }
      *(u16x8*)(w1p + i8) = o;
    } else {
      int j8 = i8 - N1_ * K_;
      vf4 a = *(const vf4*)(out_w + j8);
      vf4 b = *(const vf4*)(out_w + j8 + 4);
#pragma unroll
      for (int j = 0; j < 4; ++j) { o[j] = f2bf(a[j]); o[j + 4] = f2bf(b[j]); }
      *(u16x8*)(w2 + j8) = o;
    }
    return;
  }
  if (blockIdx.x == NCAST_ && threadIdx.x < 32) stats[threadIdx.x] = 0.f;
  int i4 = ((blockIdx.x - NCAST_) * 256 + threadIdx.x) * 4;
  int c = i4 & (C_ - 1);
  int t = (i4 >> 10) & (T_ - 1);
  vf4 acc = *(const vf4*)(cb + c);
  vf4 w0 = *(const vf4*)(cw + (size_t)c * 4);
  vf4 w1 = *(const vf4*)(cw + (size_t)(c + 1) * 4);
  vf4 w2v = *(const vf4*)(cw + (size_t)(c + 2) * 4);
  vf4 w3 = *(const vf4*)(cw + (size_t)(c + 3) * 4);
#pragma unroll
  for (int k = 0; k < 4; ++k) {
    if (t - 3 + k >= 0) {
      vf4 xv = *(const vf4*)(x + (size_t)i4 + (size_t)(k - 3) * C_);
      acc[0] = fmaf(w0[k], xv[0], acc[0]);
      acc[1] = fmaf(w1[k], xv[1], acc[1]);
      acc[2] = fmaf(w2v[k], xv[2], acc[2]);
      acc[3] = fmaf(w3[k], xv[3], acc[3]);
    }
  }
  u16x4 o;
#pragma unroll
  for (int j = 0; j < 4; ++j) {
    float s = acc[j] / (1.f + __expf(-acc[j]));
    o[j] = f2bf(s);
  }
  *(u16x4*)(xc + i4) = o;
}

// ---------------- bf16 MFMA GEMM, C[m][n] = sum_k A[m][k] * Bw[n][k] ----------------
// EPI 0 (gates, interleaved col = ch*4+gate): bias preloaded (4 regs), tanh on z
//   lanes, stash bf16 tile in LDS -> vectorized 16B global stores -> fused passA
//   chunk summaries from the stash (bit-identical to reading gates from HBM).
// EPI 1: acc+bias stashed fp32 in LDS (two half-tiles) -> float4 resid add ->
//   float4 stores.
template <int EPI>
__global__ __launch_bounds__(256, 3)
void gemm_bt(const u16* __restrict__ A, const u16* __restrict__ Bw,
             const float* __restrict__ bias, const float* __restrict__ resid,
             u16* __restrict__ obf, float* __restrict__ of32,
             f32x4* __restrict__ sSum, int M, int N, int K)
{
  __shared__ __align__(16) u16 smem[128 * 136];   // 34.8 KB; staging uses first 32 KB
  u16* a_s = smem;
  u16* b_s = smem + 128 * 64;

  const int tid  = threadIdx.x;
  const int lane = tid & 63;
  const int l15  = lane & 15;
  const int q    = lane >> 4;
  const int wave = tid >> 6;
  const int wm   = (wave >> 1) * 64;
  const int wn   = (wave & 1) * 64;
  const int bm   = blockIdx.y * 128;
  const int bn   = blockIdx.x * 128;

  const int srow   = wave * 8 + (lane >> 3);
  const int schunk = lane & 7;

  // per-thread bias (columns depend only on sn)
  float bias4[4];
#pragma unroll
  for (int sn = 0; sn < 4; ++sn) {
    int gcol = bn + wn + sn * 16 + l15;
    bias4[sn] = (EPI == 0) ? bias[((gcol & 3) << 10) | (gcol >> 2)] : bias[gcol];
  }
  const bool zlane = (EPI == 0) && ((l15 & 3) == 2);

  f32x4 acc[4][4];
#pragma unroll
  for (int i = 0; i < 4; ++i)
#pragma unroll
    for (int j = 0; j < 4; ++j) acc[i][j] = (f32x4){0.f, 0.f, 0.f, 0.f};

  for (int k0 = 0; k0 < K; k0 += 64) {
#pragma unroll
    for (int i = 0; i < 4; ++i) {
      int r = i * 32 + srow;
      int lc = schunk ^ (r & 7);
      const u16* ga = A  + (size_t)(bm + r) * K + k0 + lc * 8;
      const u16* gb = Bw + (size_t)(bn + r) * K + k0 + lc * 8;
      __builtin_amdgcn_global_load_lds(
          (const __attribute__((address_space(1))) u32*)ga,
          (__attribute__((address_space(3))) u32*)&a_s[(i * 32 + wave * 8) * 64],
          16, 0, 0);
      __builtin_amdgcn_global_load_lds(
          (const __attribute__((address_space(1))) u32*)gb,
          (__attribute__((address_space(3))) u32*)&b_s[(i * 32 + wave * 8) * 64],
          16, 0, 0);
    }
    __syncthreads();
#pragma unroll
    for (int kk = 0; kk < 64; kk += 32) {
      const int kc = kk >> 3;
      bf16x8 af[4], bfr[4];
#pragma unroll
      for (int s = 0; s < 4; ++s) {
        int ra = wm + s * 16 + l15;
        int ph = (kc + q) ^ (ra & 7);
        af[s] = *(const bf16x8*)&a_s[ra * 64 + ph * 8];
      }
#pragma unroll
      for (int s = 0; s < 4; ++s) {
        int rb = wn + s * 16 + l15;
        int ph = (kc + q) ^ (rb & 7);
        bfr[s] = *(const bf16x8*)&b_s[rb * 64 + ph * 8];
      }
#pragma unroll
      for (int sm = 0; sm < 4; ++sm)
#pragma unroll
        for (int sn = 0; sn < 4; ++sn)
          acc[sm][sn] = __builtin_amdgcn_mfma_f32_16x16x32_bf16(af[sm], bfr[sn], acc[sm][sn], 0, 0, 0);
    }
    __syncthreads();
  }

  if (EPI == 0) {
    // stash bf16 tile in LDS (stride 136 u16 = 272 B, 16B-aligned rows)
#pragma unroll
    for (int smi = 0; smi < 4; ++smi) {
#pragma unroll
      for (int r = 0; r < 4; ++r) {
        int lrow = wm + smi * 16 + q * 4 + r;
#pragma unroll
        for (int sni = 0; sni < 4; ++sni) {
          int lcol = wn + sni * 16 + l15;
          float v = acc[smi][sni][r] + bias4[sni];
          if (zlane) {
            float e = __expf(2.f * v);
            v = (e - 1.f) / (e + 1.f);
          }
          smem[lrow * 136 + lcol] = f2bf(v);
        }
      }
    }
    __syncthreads();
    // vectorized global stores: 8 x 16B per thread
#pragma unroll
    for (int it = 0; it < 8; ++it) {
      int flat = it * 256 + tid;               // 0..2047
      int row = flat >> 4;
      int ch  = flat & 15;
      u16x8 vv = *(const u16x8*)&smem[row * 136 + ch * 8];
      *(u16x8*)(obf + (size_t)(bm + row) * N + bn + ch * 8) = vv;
    }
    // fused passA: 32 channels x 4 chunks of 32 timesteps
    if (tid < 128) {
      int ch = tid & 31, ck = tid >> 5;
      const u16* sp = smem + (ck * 32) * 136 + ch * 4;
      float F = 0.f, Mx = -1e30f, aBc = 0.f, aBn = 0.f;
#pragma unroll 8
      for (int t = 0; t < CHUNK_; ++t) {
        u16x4 gv = *(const u16x4*)(sp + t * 136);
        float i_t = b2f(gv[0]), f_t = b2f(gv[1]), z_t = b2f(gv[2]);
        float Mf = Mx + f_t;
        float Mn = fmaxf(Mf, i_t);
        float ea = __expf(Mf - Mn), eb = __expf(i_t - Mn);
        aBc = ea * aBc + eb * z_t;
        aBn = ea * aBn + eb;
        F += f_t; Mx = Mn;
      }
      int b = bm >> 11;
      int s = ((bm & 2047) >> 5) + ck;
      int cg = (bn >> 2) + ch;
      sSum[(size_t)s * LANES_ + b * C_ + cg] = (f32x4){F, Mx, aBc, aBn};
    }
  } else {
    // two half-tiles through LDS as fp32 (64 x 132 floats = 33.8 KB)
    float* fs = (float*)smem;
#pragma unroll
    for (int h = 0; h < 2; ++h) {
      __syncthreads();
#pragma unroll
      for (int smi2 = 0; smi2 < 2; ++smi2) {
        int smi = 2 * h + smi2;
#pragma unroll
        for (int r = 0; r < 4; ++r) {
          int slot = (wm >> 1) + smi2 * 16 + q * 4 + r;   // 0..63
#pragma unroll
          for (int sni = 0; sni < 4; ++sni) {
            int lcol = wn + sni * 16 + l15;
            fs[slot * 132 + lcol] = acc[smi][sni][r] + bias4[sni];
          }
        }
      }
      __syncthreads();
#pragma unroll
      for (int it = 0; it < 8; ++it) {
        int flat = it * 256 + tid;             // 0..2047
        int slot = flat >> 5;                  // 0..63
        int c4 = (flat & 31) * 4;
        int absrow = bm + ((slot & 32) << 1) + (h << 5) + (slot & 31);
        vf4 v = *(const vf4*)&fs[slot * 132 + c4];
        vf4 rv = *(const vf4*)(resid + (size_t)absrow * N + bn + c4);
        v[0] += rv[0]; v[1] += rv[1]; v[2] += rv[2]; v[3] += rv[3];
        *(vf4*)(of32 + (size_t)absrow * N + bn + c4) = v;
      }
    }
  }
}

// ---------------- prefix: fold 64 chunk summaries per lane; float4-packed ----------------
__global__ void scan_prefix(const f32x4* __restrict__ sSum, f32x4* __restrict__ iSt) {
  int l = blockIdx.x * 256 + threadIdx.x;       // 0..4095
  float ct = 0.f, nt = 1.f, mt = 0.f;           // reference init (c=0, n=1, m=0)
#pragma unroll 8
  for (int s = 0; s < NCHUNK_; ++s) {
    int idx = s * LANES_ + l;
    f32x4 S = sSum[idx];
    iSt[idx] = (f32x4){ct, nt, mt, 0.f};
    float mf = mt + S[0];
    float mn = fmaxf(mf, S[1]);
    float a = __expf(mf - mn);
    float bcoef = __expf(S[1] - mn);
    ct = a * ct + bcoef * S[2];
    nt = a * nt + bcoef * S[3];
    mt = mn;
  }
}

// ---------------- passB: exact reference replay per chunk + fused GN stats ----------------
__global__ void scan_passB(const u16* __restrict__ gates, const f32x4* __restrict__ iSt,
                           u16* __restrict__ h, float* __restrict__ stats) {
  int tid = blockIdx.x * 256 + threadIdx.x;
  int lp = tid & 2047;
  int s = tid >> 11;
  int b = lp >> 9;
  int c2 = (lp & 511) * 2;
  const u16* g = gates + ((size_t)(b * T_ + s * CHUNK_) * C_ + c2) * 4;
  u16* hp = h + (size_t)(b * T_ + s * CHUNK_) * C_ + c2;
  int idx = s * LANES_ + b * C_ + c2;
  f32x4 S0 = iSt[idx], S1 = iSt[idx + 1];
  float cc0 = S0[0], nn0 = S0[1], mm0 = S0[2];
  float cc1 = S1[0], nn1 = S1[1], mm1 = S1[2];
  float ls = 0.f, lq = 0.f;
#pragma unroll 4
  for (int t = 0; t < CHUNK_; ++t) {
    u16x8 gv = *(const u16x8*)(g + (size_t)t * C_ * 4);   // [i0 f0 z0 o0 i1 f1 z1 o1]
    float h0, h1;
    {
      float i_t = b2f(gv[0]), f_t = b2f(gv[1]), z_t = b2f(gv[2]), o_t = b2f(gv[3]);
      float m_new = fmaxf(f_t + mm0, i_t);
      float i_p = __expf(i_t - m_new);
      float f_p = __expf(f_t + mm0 - m_new);
      cc0 = f_p * cc0 + i_p * z_t;
      nn0 = f_p * nn0 + i_p;
      mm0 = m_new;
      float sig_o = 1.f / (1.f + __expf(-o_t));
      h0 = sig_o * (cc0 / (nn0 + 1e-6f));
    }
    {
      float i_t = b2f(gv[4]), f_t = b2f(gv[5]), z_t = b2f(gv[6]), o_t = b2f(gv[7]);
      float m_new = fmaxf(f_t + mm1, i_t);
      float i_p = __expf(i_t - m_new);
      float f_p = __expf(f_t + mm1 - m_new);
      cc1 = f_p * cc1 + i_p * z_t;
      nn1 = f_p * nn1 + i_p;
      mm1 = m_new;
      float sig_o = 1.f / (1.f + __expf(-o_t));
      h1 = sig_o * (cc1 / (nn1 + 1e-6f));
    }
    u16 hb0 = f2bf(h0), hb1 = f2bf(h1);
    float v0 = b2f(hb0), v1 = b2f(hb1);
    ls += v0 + v1; lq += v0 * v0 + v1 * v1;
    *(u32*)(hp + (size_t)t * C_) = (u32)hb0 | ((u32)hb1 << 16);
  }
  __shared__ float rs[256], rq[256];
  int thr = threadIdx.x;
  rs[thr] = ls; rq[thr] = lq;
  __syncthreads();
  for (int off = 64; off > 0; off >>= 1) {
    if ((thr & 127) < off) { rs[thr] += rs[thr + off]; rq[thr] += rq[thr + off]; }
    __syncthreads();
  }
  if ((thr & 127) == 0) {
    int grp = b * 4 + (c2 >> 8);
    atomicAdd(&stats[grp * 2 + 0], rs[thr]);
    atomicAdd(&stats[grp * 2 + 1], rq[thr]);
  }
}

// ---------------- apply GroupNorm -> bf16 hn (8 elems/thread) ----------------
__global__ void norm_kernel(const u16* __restrict__ h, const float* __restrict__ stats,
                            const float* __restrict__ gn_w, const float* __restrict__ gn_b,
                            u16* __restrict__ hn) {
  int i8 = (blockIdx.x * 256 + threadIdx.x) * 8;
  int c = i8 & (C_ - 1);
  int b = i8 >> 21;
  int grp = b * 4 + (c >> 8);
  const float inv_n = 1.f / (float)(T_ * D_);
  float mean = stats[grp * 2 + 0] * inv_n;
  float var  = stats[grp * 2 + 1] * inv_n - mean * mean;
  float rstd = rsqrtf(var + 1e-5f);
  u16x8 hv = *(const u16x8*)(h + i8);
  vf4 w0 = *(const vf4*)(gn_w + c), w1 = *(const vf4*)(gn_w + c + 4);
  vf4 b0 = *(const vf4*)(gn_b + c), b1 = *(const vf4*)(gn_b + c + 4);
  u16x8 o;
#pragma unroll
  for (int j = 0; j < 4; ++j) {
    o[j]     = f2bf((b2f(hv[j])     - mean) * rstd * w0[j] + b0[j]);
    o[j + 4] = f2bf((b2f(hv[j + 4]) - mean) * rstd * w1[j] + b1[j]);
  }
  *(u16x8*)(hn + i8) = o;
}

extern "C" void kernel_launch(void* const* d_in, const int* in_sizes, int n_in,
                              void* d_out, int out_size, void* d_ws, size_t ws_size,
                              hipStream_t stream) {
  const float* x      = (const float*)d_in[0];
  const float* conv_w = (const float*)d_in[1];
  const float* conv_b = (const float*)d_in[2];
  const float* wx_w   = (const float*)d_in[3];
  const float* wx_b   = (const float*)d_in[4];
  const float* gn_w   = (const float*)d_in[5];
  const float* gn_b   = (const float*)d_in[6];
  const float* out_w  = (const float*)d_in[7];
  const float* out_b  = (const float*)d_in[8];
  float* out = (float*)d_out;

  char* p = (char*)d_ws;
  u16* xc    = (u16*)p; p += (size_t)M_ * K_ * 2;      // 16.8 MB
  u16* w1    = (u16*)p; p += (size_t)N1_ * K_ * 2;     // 8.4 MB (permuted)
  u16* w2    = (u16*)p; p += (size_t)C_ * C_ * 2;      // 2.1 MB
  u16* gts   = (u16*)p; p += (size_t)M_ * N1_ * 2;     // 67.1 MB (interleaved c*4+g)
  u16* hb    = (u16*)p; p += (size_t)M_ * C_ * 2;      // 16.8 MB
  u16* hn    = (u16*)p; p += (size_t)M_ * C_ * 2;      // 16.8 MB
  float* stats = (float*)p; p += 256;
  const int nsum = LANES_ * NCHUNK_;                   // 256K
  f32x4* sSum = (f32x4*)p; p += (size_t)nsum * 16;     // 4 MB
  f32x4* iSt  = (f32x4*)p; p += (size_t)nsum * 16;     // 4 MB

  // merged prologue: weight casts + conv/silu (also zeroes stats)
  prep_kernel<<<NCAST_ + (M_ * C_) / 1024, 256, 0, stream>>>(
      wx_w, out_w, w1, w2, x, conv_w, conv_b, xc, stats);

  // gates GEMM + fused passA
  gemm_bt<0><<<dim3(N1_ / 128, M_ / 128), 256, 0, stream>>>(
      xc, w1, wx_b, nullptr, gts, nullptr, sSum, M_, N1_, K_);

  // prefix + replay
  scan_prefix<<<LANES_ / 256, 256, 0, stream>>>(sSum, iSt);
  scan_passB<<<(2048 * NCHUNK_) / 256, 256, 0, stream>>>(gts, iSt, hb, stats);

  // GroupNorm apply
  norm_kernel<<<(M_ * C_) / 2048, 256, 0, stream>>>(hb, stats, gn_w, gn_b, hn);

  // output GEMM + bias + residual
  gemm_bt<1><<<dim3(C_ / 128, M_ / 128), 256, 0, stream>>>(
      hn, w2, out_b, x, nullptr, out, nullptr, M_, C_, K_);
}